// Round 1
// baseline (547.960 us; speedup 1.0000x reference)
//
#include <hip/hip_runtime.h>
#include <hip/hip_bf16.h>
#include <cstdint>

#define IN_CH 128
#define HC    64
#define ED    16
#define SLOPE 0.2f

// ---------------- Kernel 1: h = x@W, a_src, a_dst --------------------------
__global__ __launch_bounds__(256) void k_node(
    const float* __restrict__ x, const float* __restrict__ W,
    const float* __restrict__ att_src_p, const float* __restrict__ att_dst_p,
    float* __restrict__ h, float* __restrict__ a_src, float* __restrict__ a_dst,
    int N)
{
  int lane = threadIdx.x & 63;
  int gw = (blockIdx.x * blockDim.x + threadIdx.x) >> 6;
  int nwaves = (gridDim.x * blockDim.x) >> 6;
  float asv = att_src_p[lane];
  float adv = att_dst_p[lane];
  for (int n0 = gw * 4; n0 < N; n0 += nwaves * 4) {
    int n1 = min(n0 + 1, N - 1), n2 = min(n0 + 2, N - 1), n3 = min(n0 + 3, N - 1);
    const float4* xa = (const float4*)(x + (size_t)n0 * IN_CH);
    const float4* xb = (const float4*)(x + (size_t)n1 * IN_CH);
    const float4* xc = (const float4*)(x + (size_t)n2 * IN_CH);
    const float4* xd = (const float4*)(x + (size_t)n3 * IN_CH);
    float acc0 = 0.f, acc1 = 0.f, acc2 = 0.f, acc3 = 0.f;
#pragma unroll 4
    for (int k4 = 0; k4 < IN_CH / 4; k4++) {
      float4 va = xa[k4], vb = xb[k4], vc = xc[k4], vd = xd[k4];
      float w0 = W[(k4 * 4 + 0) * HC + lane];
      float w1 = W[(k4 * 4 + 1) * HC + lane];
      float w2 = W[(k4 * 4 + 2) * HC + lane];
      float w3 = W[(k4 * 4 + 3) * HC + lane];
      acc0 += va.x * w0 + va.y * w1 + va.z * w2 + va.w * w3;
      acc1 += vb.x * w0 + vb.y * w1 + vb.z * w2 + vb.w * w3;
      acc2 += vc.x * w0 + vc.y * w1 + vc.z * w2 + vc.w * w3;
      acc3 += vd.x * w0 + vd.y * w1 + vd.z * w2 + vd.w * w3;
    }
    h[(size_t)n0 * HC + lane] = acc0;
    if (n0 + 1 < N) h[(size_t)n1 * HC + lane] = acc1;
    if (n0 + 2 < N) h[(size_t)n2 * HC + lane] = acc2;
    if (n0 + 3 < N) h[(size_t)n3 * HC + lane] = acc3;
    float s0 = acc0 * asv, s1 = acc1 * asv, s2 = acc2 * asv, s3 = acc3 * asv;
    float d0 = acc0 * adv, d1 = acc1 * adv, d2 = acc2 * adv, d3 = acc3 * adv;
#pragma unroll
    for (int m = 1; m < 16; m <<= 1) {
      s0 += __shfl_xor(s0, m); s1 += __shfl_xor(s1, m);
      s2 += __shfl_xor(s2, m); s3 += __shfl_xor(s3, m);
      d0 += __shfl_xor(d0, m); d1 += __shfl_xor(d1, m);
      d2 += __shfl_xor(d2, m); d3 += __shfl_xor(d3, m);
    }
    if ((lane & 15) == 0) {
      int hh = lane >> 4;
      a_src[(size_t)n0 * 4 + hh] = s0; a_dst[(size_t)n0 * 4 + hh] = d0;
      if (n0 + 1 < N) { a_src[(size_t)n1 * 4 + hh] = s1; a_dst[(size_t)n1 * 4 + hh] = d1; }
      if (n0 + 2 < N) { a_src[(size_t)n2 * 4 + hh] = s2; a_dst[(size_t)n2 * 4 + hh] = d2; }
      if (n0 + 3 < N) { a_src[(size_t)n3 * 4 + hh] = s3; a_dst[(size_t)n3 * 4 + hh] = d3; }
    }
  }
}

// ---------------- Kernel 2: degree histogram over dst ----------------------
__global__ __launch_bounds__(256) void k_hist(const int* __restrict__ dst, int E,
                                              int* __restrict__ deg)
{
  int e = blockIdx.x * 256 + threadIdx.x;
  if (e < E) atomicAdd(&deg[dst[e]], 1);
}

// ---------------- Kernel 3a/3b/3c: exclusive scan -> rowptr ----------------
__global__ __launch_bounds__(256) void k_scan_a(const int* __restrict__ deg, int N,
                                                int* __restrict__ rowptr,
                                                int* __restrict__ blksums)
{
  __shared__ int tsum[256];
  int tid = threadIdx.x;
  int base = blockIdx.x * 2048 + tid * 8;
  int pre[8];
  int s = 0;
#pragma unroll
  for (int j = 0; j < 8; j++) {
    int idx = base + j;
    int v = (idx < N) ? deg[idx] : 0;
    pre[j] = s; s += v;
  }
  tsum[tid] = s;
  __syncthreads();
  for (int offm = 1; offm < 256; offm <<= 1) {
    int t = (tid >= offm) ? tsum[tid - offm] : 0;
    __syncthreads();
    tsum[tid] += t;
    __syncthreads();
  }
  int excl = tsum[tid] - s;
#pragma unroll
  for (int j = 0; j < 8; j++) {
    int idx = base + j;
    if (idx < N) rowptr[idx] = excl + pre[j];
  }
  if (tid == 255) blksums[blockIdx.x] = tsum[255];
}

__global__ void k_scan_b(int* __restrict__ blksums, int NB)
{
  if (threadIdx.x == 0 && blockIdx.x == 0) {
    int run = 0;
    for (int b = 0; b < NB; b++) { int t = blksums[b]; blksums[b] = run; run += t; }
  }
}

__global__ __launch_bounds__(256) void k_scan_c(int* __restrict__ rowptr,
                                                const int* __restrict__ blksums,
                                                int N, int E)
{
  int i = blockIdx.x * 256 + threadIdx.x;
  if (i < N) rowptr[i] += blksums[i >> 11];
  if (i == 0) rowptr[N] = E;
}

// ---------------- Kernel 4: per-edge logits + exp + scatter to CSR ---------
__global__ __launch_bounds__(256) void k_edge(
    const int* __restrict__ ei, const float* __restrict__ ea,
    const float* __restrict__ W_edge, const float* __restrict__ att_edge,
    const float* __restrict__ a_src, const float* __restrict__ a_dst,
    const int* __restrict__ rowptr, int* __restrict__ cursor,
    int* __restrict__ src_sorted, float* __restrict__ ex_sorted, int E)
{
  __shared__ float ve[ED * 4];   // v_edge[d][h] = sum_c W_edge[d, h*16+c]*att_edge[h,c]
  if (threadIdx.x < 64) {
    int d = threadIdx.x >> 2, hh = threadIdx.x & 3;
    float s = 0.f;
#pragma unroll
    for (int c = 0; c < 16; c++) s += W_edge[d * HC + hh * 16 + c] * att_edge[hh * 16 + c];
    ve[d * 4 + hh] = s;
  }
  __syncthreads();
  int e = blockIdx.x * 256 + threadIdx.x;
  if (e >= E) return;
  int sn = ei[e], dn = ei[E + e];
  float4 as4 = *(const float4*)(a_src + (size_t)sn * 4);
  float4 ad4 = *(const float4*)(a_dst + (size_t)dn * 4);
  const float4* ea4 = (const float4*)(ea + (size_t)e * ED);
  float4 q0 = ea4[0], q1 = ea4[1], q2 = ea4[2], q3 = ea4[3];
  float eav[16] = {q0.x,q0.y,q0.z,q0.w, q1.x,q1.y,q1.z,q1.w,
                   q2.x,q2.y,q2.z,q2.w, q3.x,q3.y,q3.z,q3.w};
  float ae0 = 0.f, ae1 = 0.f, ae2 = 0.f, ae3 = 0.f;
#pragma unroll
  for (int d = 0; d < ED; d++) {
    float v = eav[d];
    ae0 += v * ve[d * 4 + 0]; ae1 += v * ve[d * 4 + 1];
    ae2 += v * ve[d * 4 + 2]; ae3 += v * ve[d * 4 + 3];
  }
  float al0 = as4.x + ad4.x + ae0;
  float al1 = as4.y + ad4.y + ae1;
  float al2 = as4.z + ad4.z + ae2;
  float al3 = as4.w + ad4.w + ae3;
  al0 = al0 > 0.f ? al0 : SLOPE * al0;
  al1 = al1 > 0.f ? al1 : SLOPE * al1;
  al2 = al2 > 0.f ? al2 : SLOPE * al2;
  al3 = al3 > 0.f ? al3 : SLOPE * al3;
  float ex0 = __expf(al0), ex1 = __expf(al1), ex2 = __expf(al2), ex3 = __expf(al3);
  int pos = rowptr[dn] + atomicAdd(&cursor[dn], 1);
  src_sorted[pos] = sn;
  *(float4*)(ex_sorted + (size_t)pos * 4) = make_float4(ex0, ex1, ex2, ex3);
}

// ---------------- Kernel 5: per-node pull aggregation ----------------------
__global__ __launch_bounds__(256) void k_agg(
    const float* __restrict__ h,
    const float* __restrict__ a_src, const float* __restrict__ a_dst,
    const float* __restrict__ W_edge, const float* __restrict__ att_edge,
    const float* __restrict__ bias, const int* __restrict__ rowptr,
    const int* __restrict__ src_sorted, const float* __restrict__ ex_sorted,
    float* __restrict__ out, int N)
{
  __shared__ float aes[4];       // self-loop edge logit: sum_d v_edge[d][h]*1.0
  if (threadIdx.x < 4) {
    int hh = threadIdx.x;
    float s = 0.f;
    for (int d = 0; d < ED; d++) {
      float vd = 0.f;
#pragma unroll
      for (int c = 0; c < 16; c++) vd += W_edge[d * HC + hh * 16 + c] * att_edge[hh * 16 + c];
      s += vd;
    }
    aes[hh] = s;
  }
  __syncthreads();
  int lane = threadIdx.x & 63;
  int n = blockIdx.x * 4 + (threadIdx.x >> 6);
  if (n >= N) return;
  int hh = lane >> 4;
  int b = rowptr[n], e = rowptr[n + 1];
  float acc = 0.f, den = 0.f;
  int p = b;
  for (; p + 1 < e; p += 2) {
    int s0 = src_sorted[p], s1 = src_sorted[p + 1];
    float x0 = ex_sorted[(size_t)p * 4 + hh];
    float x1 = ex_sorted[(size_t)(p + 1) * 4 + hh];
    float h0 = h[(size_t)s0 * HC + lane];
    float h1 = h[(size_t)s1 * HC + lane];
    acc += x0 * h0; den += x0;
    acc += x1 * h1; den += x1;
  }
  if (p < e) {
    int s0 = src_sorted[p];
    float x0 = ex_sorted[(size_t)p * 4 + hh];
    acc += x0 * h[(size_t)s0 * HC + lane]; den += x0;
  }
  // self loop (edge_attr filled with 1.0)
  float al = a_src[(size_t)n * 4 + hh] + a_dst[(size_t)n * 4 + hh] + aes[hh];
  al = al > 0.f ? al : SLOPE * al;
  float exs = __expf(al);
  acc += exs * h[(size_t)n * HC + lane];
  den += exs;
  out[(size_t)n * HC + lane] = acc / den + bias[lane];
}

// ---------------- Launcher -------------------------------------------------
extern "C" void kernel_launch(void* const* d_in, const int* in_sizes, int n_in,
                              void* d_out, int out_size, void* d_ws, size_t ws_size,
                              hipStream_t stream)
{
  const float* x        = (const float*)d_in[0];
  const int*   ei       = (const int*)d_in[1];
  const float* ea       = (const float*)d_in[2];
  const float* W        = (const float*)d_in[3];
  const float* att_src  = (const float*)d_in[4];
  const float* att_dst  = (const float*)d_in[5];
  const float* W_edge   = (const float*)d_in[6];
  const float* att_edge = (const float*)d_in[7];
  const float* bias     = (const float*)d_in[8];
  float* out = (float*)d_out;

  int N = in_sizes[0] / IN_CH;
  int E = in_sizes[1] / 2;

  uint8_t* ws = (uint8_t*)d_ws;
  size_t off = 0;
  auto alloc = [&](size_t bytes) -> void* {
    void* p = ws + off;
    off = (off + bytes + 255) & ~(size_t)255;
    return p;
  };
  float* h        = (float*)alloc((size_t)N * HC * 4);
  float* a_src_w  = (float*)alloc((size_t)N * 4 * 4);
  float* a_dst_w  = (float*)alloc((size_t)N * 4 * 4);
  int*   deg      = (int*)alloc((size_t)N * 2 * 4);   // deg then cursor, one memset
  int*   cursor   = deg + N;
  int*   rowptr   = (int*)alloc(((size_t)N + 1) * 4);
  int*   blksums  = (int*)alloc(64 * 4);
  int*   src_sorted = (int*)alloc((size_t)E * 4);
  float* ex_sorted  = (float*)alloc((size_t)E * 4 * 4);
  (void)ws_size; (void)n_in; (void)out_size;

  hipMemsetAsync(deg, 0, (size_t)N * 2 * 4, stream);

  k_node<<<512, 256, 0, stream>>>(x, W, att_src, att_dst, h, a_src_w, a_dst_w, N);
  k_hist<<<(E + 255) / 256, 256, 0, stream>>>(ei + E, E, deg);
  int NB = (N + 2047) / 2048;
  k_scan_a<<<NB, 256, 0, stream>>>(deg, N, rowptr, blksums);
  k_scan_b<<<1, 64, 0, stream>>>(blksums, NB);
  k_scan_c<<<(N + 255) / 256, 256, 0, stream>>>(rowptr, blksums, N, E);
  k_edge<<<(E + 255) / 256, 256, 0, stream>>>(ei, ea, W_edge, att_edge,
                                              a_src_w, a_dst_w, rowptr, cursor,
                                              src_sorted, ex_sorted, E);
  k_agg<<<(N + 3) / 4, 256, 0, stream>>>(h, a_src_w, a_dst_w, W_edge, att_edge,
                                         bias, rowptr, src_sorted, ex_sorted, out, N);
}